// Round 5
// baseline (262.574 us; speedup 1.0000x reference)
//
#include <hip/hip_runtime.h>
#include <math.h>

#define NUM_AGENTS   128
#define NUM_HIVES    64
#define NUM_ENTITIES 192

// One block per batch element. 256 threads = 4 waves.
// out[0] = vote_cost + movement_cost (scalar, atomicAdd-accumulated)
// out[1 + b] = max_freq[b]
__global__ __launch_bounds__(256) void bee_kernel(
    const float* __restrict__ movements,    // (B, 192, 2)
    const float* __restrict__ votes,        // (B, 128, 64)
    const float* __restrict__ hive_values,  // (B, 64, 1)
    float* __restrict__ out)
{
    const int b    = blockIdx.x;
    const int tid  = threadIdx.x;
    const int lane = tid & 63;
    const int wave = tid >> 6;

    __shared__ float hv[NUM_HIVES];
    __shared__ int   counts[NUM_HIVES];
    __shared__ float mc_s[4];
    __shared__ float vs_s[4];

    if (tid < NUM_HIVES) {
        hv[tid]     = hive_values[(size_t)b * NUM_HIVES + tid];
        counts[tid] = 0;
    }
    __syncthreads();

    // ---- movement cost partial: 192 entities, float2 coalesced ----
    float mc = 0.0f;
    if (tid < NUM_ENTITIES) {
        float2 m = ((const float2*)movements)[(size_t)b * NUM_ENTITIES + tid];
        mc = sqrtf(m.x * m.x + m.y * m.y);
    }

    // ---- per-agent argmax over 64 hives ----
    // 16 lanes per agent, each lane loads a float4 (row of 64 floats = 16 float4).
    // 4 agents per wave per iteration; 4 waves -> 16 agents/iter; 8 iters = 128 agents.
    const int grp = lane >> 4;   // 0..3: which agent within the wave
    const int gl  = lane & 15;   // lane within the 16-lane group
    const float4* vbase = (const float4*)(votes + (size_t)b * NUM_AGENTS * NUM_HIVES);

    float vsum = 0.0f;
    #pragma unroll
    for (int iter = 0; iter < 8; ++iter) {
        const int a = iter * 16 + wave * 4 + grp;
        float4 v = vbase[a * 16 + gl];

        float bestv = v.x; int besti = gl * 4;
        if (v.y > bestv) { bestv = v.y; besti = gl * 4 + 1; }
        if (v.z > bestv) { bestv = v.z; besti = gl * 4 + 2; }
        if (v.w > bestv) { bestv = v.w; besti = gl * 4 + 3; }

        // butterfly argmax across the 16-lane group (xor 1,2,4,8 stays in-group)
        #pragma unroll
        for (int off = 1; off < 16; off <<= 1) {
            float ov = __shfl_xor(bestv, off, 64);
            int   oi = __shfl_xor(besti, off, 64);
            if (ov > bestv || (ov == bestv && oi < besti)) { bestv = ov; besti = oi; }
        }

        if (gl == 0) {
            atomicAdd(&counts[besti], 1);
            vsum += hv[besti];
        }
    }

    // ---- block reduction of mc and vsum ----
    #pragma unroll
    for (int off = 32; off > 0; off >>= 1) {
        mc   += __shfl_down(mc,   off, 64);
        vsum += __shfl_down(vsum, off, 64);
    }
    if (lane == 0) { mc_s[wave] = mc; vs_s[wave] = vsum; }
    __syncthreads();   // also makes counts[] atomics visible

    if (wave == 0) {
        int c = counts[lane];
        #pragma unroll
        for (int off = 32; off > 0; off >>= 1) {
            int oc = __shfl_down(c, off, 64);
            c = c > oc ? c : oc;
        }
        if (lane == 0) {
            float mc_t = mc_s[0] + mc_s[1] + mc_s[2] + mc_s[3];
            float vs_t = vs_s[0] + vs_s[1] + vs_s[2] + vs_s[3];
            float mf = (float)c / (float)NUM_AGENTS;
            out[1 + b] = mf;
            // discount = 100*(1 - sigmoid(30*(mf-0.7))) = 100 / (1 + exp(30*(mf-0.7)))
            float discount = 100.0f / (1.0f + expf(30.0f * (mf - 0.7f)));
            float contrib = mc_t - vs_t / discount;   // movement partial + (-value/discount)
            atomicAdd(out, contrib);
        }
    }
}

extern "C" void kernel_launch(void* const* d_in, const int* in_sizes, int n_in,
                              void* d_out, int out_size, void* d_ws, size_t ws_size,
                              hipStream_t stream) {
    const float* movements   = (const float*)d_in[0];
    // d_in[1] = utterances (unused by reference)
    const float* votes       = (const float*)d_in[2];
    const float* hive_values = (const float*)d_in[3];
    // d_in[4] = locations (unused by reference)
    float* out = (float*)d_out;

    const int B = in_sizes[3] / NUM_HIVES;   // 4096

    // out[0] is accumulated via atomicAdd; harness poisons d_out -> zero it.
    hipMemsetAsync(out, 0, sizeof(float), stream);

    bee_kernel<<<B, 256, 0, stream>>>(movements, votes, hive_values, out);
}

// Round 11
// 235.902 us; speedup vs baseline: 1.1131x; 1.1131x over previous
//
#include <hip/hip_runtime.h>
#include <math.h>

#define NUM_AGENTS   128
#define NUM_HIVES    64
#define NUM_ENTITIES 192

// One block per batch element. 256 threads = 4 waves.
// Writes per-block scalar partial to ws_partial[b] (NO same-address atomics),
// and out[1 + b] = max_freq[b]. A second kernel reduces ws_partial -> out[0].
__global__ __launch_bounds__(256) void bee_kernel(
    const float* __restrict__ movements,    // (B, 192, 2)
    const float* __restrict__ votes,        // (B, 128, 64)
    const float* __restrict__ hive_values,  // (B, 64, 1)
    float* __restrict__ ws_partial,         // (B,)
    float* __restrict__ out)
{
    const int b    = blockIdx.x;
    const int tid  = threadIdx.x;
    const int lane = tid & 63;
    const int wave = tid >> 6;

    __shared__ float hv[NUM_HIVES];
    __shared__ int   counts[NUM_HIVES];
    __shared__ float mc_s[4];
    __shared__ float vs_s[4];

    if (tid < NUM_HIVES) {
        hv[tid]     = hive_values[(size_t)b * NUM_HIVES + tid];
        counts[tid] = 0;
    }
    __syncthreads();

    // ---- movement cost partial: 192 entities, float2 coalesced ----
    float mc = 0.0f;
    if (tid < NUM_ENTITIES) {
        float2 m = ((const float2*)movements)[(size_t)b * NUM_ENTITIES + tid];
        mc = sqrtf(m.x * m.x + m.y * m.y);
    }

    // ---- per-agent argmax over 64 hives ----
    // 16 lanes per agent, each lane loads a float4; butterfly argmax in-group.
    const int grp = lane >> 4;   // 0..3: which agent within the wave
    const int gl  = lane & 15;   // lane within the 16-lane group
    const float4* vbase = (const float4*)(votes + (size_t)b * NUM_AGENTS * NUM_HIVES);

    float vsum = 0.0f;
    #pragma unroll
    for (int iter = 0; iter < 8; ++iter) {
        const int a = iter * 16 + wave * 4 + grp;
        float4 v = vbase[a * 16 + gl];

        float bestv = v.x; int besti = gl * 4;
        if (v.y > bestv) { bestv = v.y; besti = gl * 4 + 1; }
        if (v.z > bestv) { bestv = v.z; besti = gl * 4 + 2; }
        if (v.w > bestv) { bestv = v.w; besti = gl * 4 + 3; }

        // butterfly argmax across the 16-lane group (xor 1,2,4,8 stays in-group)
        #pragma unroll
        for (int off = 1; off < 16; off <<= 1) {
            float ov = __shfl_xor(bestv, off, 64);
            int   oi = __shfl_xor(besti, off, 64);
            if (ov > bestv || (ov == bestv && oi < besti)) { bestv = ov; besti = oi; }
        }

        if (gl == 0) {
            atomicAdd(&counts[besti], 1);
            vsum += hv[besti];
        }
    }

    // ---- block reduction of mc and vsum ----
    #pragma unroll
    for (int off = 32; off > 0; off >>= 1) {
        mc   += __shfl_down(mc,   off, 64);
        vsum += __shfl_down(vsum, off, 64);
    }
    if (lane == 0) { mc_s[wave] = mc; vs_s[wave] = vsum; }
    __syncthreads();   // also makes counts[] atomics visible

    if (wave == 0) {
        int c = counts[lane];
        #pragma unroll
        for (int off = 32; off > 0; off >>= 1) {
            int oc = __shfl_down(c, off, 64);
            c = c > oc ? c : oc;
        }
        if (lane == 0) {
            float mc_t = mc_s[0] + mc_s[1] + mc_s[2] + mc_s[3];
            float vs_t = vs_s[0] + vs_s[1] + vs_s[2] + vs_s[3];
            float mf = (float)c / (float)NUM_AGENTS;
            out[1 + b] = mf;
            // discount = 100*(1 - sigmoid(30*(mf-0.7))) = 100 / (1 + exp(30*(mf-0.7)))
            float discount = 100.0f / (1.0f + expf(30.0f * (mf - 0.7f)));
            // per-block contribution: movement partial + (-value/discount)
            ws_partial[b] = mc_t - vs_t / discount;
        }
    }
}

// Single block reduces B partials -> out[0]. Deterministic, no atomics.
__global__ __launch_bounds__(256) void reduce_kernel(
    const float* __restrict__ ws_partial, float* __restrict__ out, int B)
{
    const int tid  = threadIdx.x;
    const int lane = tid & 63;
    const int wave = tid >> 6;
    __shared__ float p_s[4];

    float s = 0.0f;
    const float4* w4 = (const float4*)ws_partial;
    for (int i = tid; i < B / 4; i += 256) {
        float4 v = w4[i];
        s += (v.x + v.y) + (v.z + v.w);
    }
    #pragma unroll
    for (int off = 32; off > 0; off >>= 1) s += __shfl_down(s, off, 64);
    if (lane == 0) p_s[wave] = s;
    __syncthreads();
    if (tid == 0) out[0] = p_s[0] + p_s[1] + p_s[2] + p_s[3];
}

extern "C" void kernel_launch(void* const* d_in, const int* in_sizes, int n_in,
                              void* d_out, int out_size, void* d_ws, size_t ws_size,
                              hipStream_t stream) {
    const float* movements   = (const float*)d_in[0];
    // d_in[1] = utterances (unused by reference)
    const float* votes       = (const float*)d_in[2];
    const float* hive_values = (const float*)d_in[3];
    // d_in[4] = locations (unused by reference)
    float* out = (float*)d_out;
    float* ws_partial = (float*)d_ws;   // B floats of scratch

    const int B = in_sizes[3] / NUM_HIVES;   // 4096

    bee_kernel<<<B, 256, 0, stream>>>(movements, votes, hive_values, ws_partial, out);
    reduce_kernel<<<1, 256, 0, stream>>>(ws_partial, out, B);
}